// Round 1
// baseline (662.016 us; speedup 1.0000x reference)
//
#include <hip/hip_runtime.h>
#include <math.h>

constexpr int Bv   = 8;
constexpr int Nv   = 2048;
constexpr int FIN  = 128;
constexpr int FOUT = 128;
constexpr int NH   = 2;

// ---------------- Kernel 1: Wh[b,h,n,o] = sum_f h[b,n,f] * W[h,f,o] ----------------
// grid: (N/32) * B * H blocks, 256 threads. W staged transposed in LDS (pad to 132).
__global__ __launch_bounds__(256) void wh_kernel(const float* __restrict__ h,
                                                 const float* __restrict__ W,
                                                 float* __restrict__ Wh) {
    int bid  = blockIdx.x;
    int tile = bid & 63;          // N/32 = 64
    int bh   = bid >> 6;          // 0..15
    int hh   = bh & (NH - 1);
    int bb   = bh / NH;

    __shared__ float Wt[FIN * 132];   // [o][f], stride 132 dwords (16B aligned, bank-spread)

    int t = threadIdx.x;
    const float* Wsrc = W + (size_t)hh * FIN * FOUT;
    for (int idx = t; idx < FIN * FOUT; idx += 256) {
        int f = idx >> 7;
        int o = idx & 127;
        Wt[o * 132 + f] = Wsrc[idx];
    }
    __syncthreads();

    int o    = t & 127;
    int rg   = t >> 7;
    int row0 = tile * 32 + rg * 16;

    float acc[16];
#pragma unroll
    for (int k = 0; k < 16; ++k) acc[k] = 0.f;

    const float* hbase = h + (size_t)bb * Nv * FIN;
    for (int f4 = 0; f4 < FIN; f4 += 4) {
        float4 w4 = *(const float4*)&Wt[o * 132 + f4];
#pragma unroll
        for (int k = 0; k < 16; ++k) {
            float4 h4 = *(const float4*)&hbase[(size_t)(row0 + k) * FIN + f4];
            acc[k] += h4.x * w4.x + h4.y * w4.y + h4.z * w4.z + h4.w * w4.w;
        }
    }
    float* whbase = Wh + (size_t)(bb * NH + hh) * Nv * FOUT;
#pragma unroll
    for (int k = 0; k < 16; ++k)
        whbase[(size_t)(row0 + k) * FOUT + o] = acc[k];
}

// ---------------- Kernel 1b: s_i[b,h,n] = Wh[b,h,n,:].a1[h];  s_j with a2 ----------------
// one wave per row, 4 waves/block
__global__ __launch_bounds__(256) void sij_kernel(const float* __restrict__ Wh,
                                                  const float* __restrict__ a,
                                                  float* __restrict__ si,
                                                  float* __restrict__ sj) {
    int row  = blockIdx.x * 4 + (threadIdx.x >> 6);
    int lane = threadIdx.x & 63;
    int hh   = (row / Nv) & (NH - 1);
    const float* arow = a + (size_t)hh * 2 * FOUT;

    float v0 = Wh[(size_t)row * FOUT + lane];
    float v1 = Wh[(size_t)row * FOUT + 64 + lane];
    float s1 = v0 * arow[lane] + v1 * arow[64 + lane];
    float s2 = v0 * arow[FOUT + lane] + v1 * arow[FOUT + 64 + lane];
#pragma unroll
    for (int m = 32; m >= 1; m >>= 1) {
        s1 += __shfl_xor(s1, m, 64);
        s2 += __shfl_xor(s2, m, 64);
    }
    if (lane == 0) { si[row] = s1; sj[row] = s2; }
}

// ---------------- Kernel 2: fused masked-softmax(e) @ Wh, flash style ----------------
// grid: B * (N/32) blocks, 256 threads. Both heads per block (adj read once).
// Phase A threads: (head ah, row ar) pairs x 4 lanes, TJ=64 j's per tile.
// Phase B threads: (head bh, out col bo), acc[32] rows in registers.
__global__ __launch_bounds__(256) void gat_attn_kernel(const int* __restrict__ adj,
                                                       const float* __restrict__ Wh,
                                                       const float* __restrict__ si,
                                                       const float* __restrict__ sj,
                                                       float* __restrict__ out) {
    int bid   = blockIdx.x;
    int itile = bid & 63;      // N/32 = 64
    int bb    = bid >> 6;

    __shared__ float ptile[2 * 32 * 68];   // [head][row][j] pad 68
    __shared__ float alpha[2 * 32];
    __shared__ float lsum[2 * 32];

    int t = threadIdx.x;
    // phase A identity
    int pair = t >> 2;          // 0..63
    int ah   = pair >> 5;       // head
    int ar   = pair & 31;       // row within tile
    int js   = t & 3;
    // phase B identity
    int bh = t >> 7;            // head
    int bo = t & 127;           // out col

    int arow = itile * 32 + ar;
    float s_i = si[((size_t)bb * NH + ah) * Nv + arow];
    const int*   adjrow = adj + ((size_t)bb * Nv + arow) * Nv;
    const float* sjrow  = sj + ((size_t)bb * NH + ah) * Nv;
    const float* whb    = Wh + ((size_t)bb * NH + bh) * Nv * FOUT + bo;
    const float* pbase  = ptile + bh * 32 * 68;

    float m = -1e30f, l = 0.f;
    float acc[32];
#pragma unroll
    for (int r = 0; r < 32; ++r) acc[r] = 0.f;

    for (int jt = 0; jt < Nv / 64; ++jt) {
        int jbase = jt * 64;

        // ---- phase A: scores + online softmax for (ah, ar) ----
        float e0[4], e1[4], e2[4], e3[4];
        float tmax = -1e30f;
#pragma unroll
        for (int c = 0; c < 4; ++c) {
            int j = jbase + js * 16 + c * 4;
            int4   av = *(const int4*)&adjrow[j];
            float4 sv = *(const float4*)&sjrow[j];
            float a0 = s_i + sv.x; a0 = (a0 > 0.f) ? a0 : 0.2f * a0; a0 = av.x ? a0 : -INFINITY;
            float a1 = s_i + sv.y; a1 = (a1 > 0.f) ? a1 : 0.2f * a1; a1 = av.y ? a1 : -INFINITY;
            float a2 = s_i + sv.z; a2 = (a2 > 0.f) ? a2 : 0.2f * a2; a2 = av.z ? a2 : -INFINITY;
            float a3 = s_i + sv.w; a3 = (a3 > 0.f) ? a3 : 0.2f * a3; a3 = av.w ? a3 : -INFINITY;
            e0[c] = a0; e1[c] = a1; e2[c] = a2; e3[c] = a3;
            tmax = fmaxf(tmax, fmaxf(fmaxf(a0, a1), fmaxf(a2, a3)));
        }
        tmax = fmaxf(tmax, __shfl_xor(tmax, 1, 64));
        tmax = fmaxf(tmax, __shfl_xor(tmax, 2, 64));
        float mnew = fmaxf(m, tmax);             // >= -1e30, always finite
        float alf  = __expf(m - mnew);           // finite - finite, no NaN
        float ps = 0.f;
#pragma unroll
        for (int c = 0; c < 4; ++c) {
            // exp(-INF - finite) = 0 for masked entries
            float p0 = __expf(e0[c] - mnew);
            float p1 = __expf(e1[c] - mnew);
            float p2 = __expf(e2[c] - mnew);
            float p3 = __expf(e3[c] - mnew);
            ps += (p0 + p1) + (p2 + p3);
            *(float4*)&ptile[(pair) * 68 + js * 16 + c * 4] = make_float4(p0, p1, p2, p3);
        }
        ps += __shfl_xor(ps, 1, 64);
        ps += __shfl_xor(ps, 2, 64);
        l = l * alf + ps;
        m = mnew;
        if (js == 0) alpha[pair] = alf;

        __syncthreads();

        // ---- phase B: acc[r][bo] = acc*alpha + sum_j p[r][j] * Wh[j][bo] ----
#pragma unroll
        for (int r = 0; r < 32; ++r) acc[r] *= alpha[bh * 32 + r];

        for (int j4 = 0; j4 < 64; j4 += 4) {
            float w0 = whb[(size_t)(jbase + j4 + 0) * FOUT];
            float w1 = whb[(size_t)(jbase + j4 + 1) * FOUT];
            float w2 = whb[(size_t)(jbase + j4 + 2) * FOUT];
            float w3 = whb[(size_t)(jbase + j4 + 3) * FOUT];
#pragma unroll
            for (int r = 0; r < 32; ++r) {
                float4 p4 = *(const float4*)&pbase[r * 68 + j4];
                acc[r] += p4.x * w0 + p4.y * w1 + p4.z * w2 + p4.w * w3;
            }
        }
        __syncthreads();   // protect ptile/alpha before next tile's phase A
    }

    // ---- epilogue ----
    if (js == 0) lsum[pair] = 1.0f / l;
    __syncthreads();
#pragma unroll
    for (int r = 0; r < 32; ++r) {
        int row = itile * 32 + r;
        out[((size_t)bb * Nv + row) * (NH * FOUT) + bh * FOUT + bo] = acc[r] * lsum[bh * 32 + r];
    }
}

extern "C" void kernel_launch(void* const* d_in, const int* in_sizes, int n_in,
                              void* d_out, int out_size, void* d_ws, size_t ws_size,
                              hipStream_t stream) {
    const float* h   = (const float*)d_in[0];
    const int*   adj = (const int*)d_in[1];
    const float* W   = (const float*)d_in[2];
    const float* a   = (const float*)d_in[3];
    float*       out = (float*)d_out;

    float* ws = (float*)d_ws;
    float* Wh = ws;                                     // B*H*N*FOUT = 4,194,304 floats
    float* si = ws + (size_t)Bv * NH * Nv * FOUT;       // 32768 floats
    float* sj = si + (size_t)Bv * NH * Nv;              // 32768 floats

    wh_kernel<<<dim3(Bv * NH * (Nv / 32)), dim3(256), 0, stream>>>(h, W, Wh);
    sij_kernel<<<dim3(Bv * NH * Nv / 4), dim3(256), 0, stream>>>(Wh, a, si, sj);
    gat_attn_kernel<<<dim3(Bv * (Nv / 32)), dim3(256), 0, stream>>>(adj, Wh, si, sj, out);
}

// Round 2
// 233.601 us; speedup vs baseline: 2.8340x; 2.8340x over previous
//
#include <hip/hip_runtime.h>
#include <math.h>

constexpr int Bv   = 8;
constexpr int Nv   = 2048;
constexpr int FIN  = 128;
constexpr int FOUT = 128;
constexpr int NH   = 2;

typedef __attribute__((ext_vector_type(8))) short  short8;
typedef __attribute__((ext_vector_type(4))) float  f32x4;

static __device__ __forceinline__ unsigned short f2bf(float f) {
    unsigned u = __builtin_bit_cast(unsigned, f);
    u += 0x7fffu + ((u >> 16) & 1u);          // round-to-nearest-even
    return (unsigned short)(u >> 16);
}

// ---------------- Kernel 0: wa[h][q][f] = sum_o W[h][f][o] * a[h][q*FOUT+o], q in {0,1} ----------------
__global__ void wa_kernel(const float* __restrict__ W, const float* __restrict__ a,
                          float* __restrict__ wa) {
    int t = threadIdx.x;            // 256 = NH * FIN
    int hh = t >> 7, f = t & 127;
    const float* Wr = W + ((size_t)hh * FIN + f) * FOUT;
    const float* ar = a + (size_t)hh * 2 * FOUT;
    float s1 = 0.f, s2 = 0.f;
    for (int o = 0; o < FOUT; ++o) {
        float w = Wr[o];
        s1 += w * ar[o];
        s2 += w * ar[FOUT + o];
    }
    wa[(hh * 2 + 0) * FIN + f] = s1;
    wa[(hh * 2 + 1) * FIN + f] = s2;
}

// ---------------- Kernel 1: si/sj[b,h,n] = h[b,n,:] . wa[h][q][:] ----------------
__global__ __launch_bounds__(256) void sij_kernel(const float* __restrict__ h,
                                                  const float* __restrict__ wa,
                                                  float* __restrict__ si,
                                                  float* __restrict__ sj) {
    int row  = blockIdx.x * 4 + (threadIdx.x >> 6);   // b*N + n
    int lane = threadIdx.x & 63;
    float x0 = h[(size_t)row * FIN + lane];
    float x1 = h[(size_t)row * FIN + 64 + lane];
    float s[4];
#pragma unroll
    for (int q = 0; q < 4; ++q) {
        const float* w = wa + q * FIN;
        s[q] = x0 * w[lane] + x1 * w[64 + lane];
    }
#pragma unroll
    for (int m = 32; m >= 1; m >>= 1) {
#pragma unroll
        for (int q = 0; q < 4; ++q) s[q] += __shfl_xor(s[q], m, 64);
    }
    if (lane == 0) {
        int bb = row >> 11, n = row & (Nv - 1);
        si[((size_t)(bb * NH + 0)) * Nv + n] = s[0];
        sj[((size_t)(bb * NH + 0)) * Nv + n] = s[1];
        si[((size_t)(bb * NH + 1)) * Nv + n] = s[2];
        sj[((size_t)(bb * NH + 1)) * Nv + n] = s[3];
    }
}

// ---------------- Kernel 2: WhT[b,h,o,n] = bf16( sum_f h[b,n,f] * W[h,f,o] ) ----------------
__global__ __launch_bounds__(256) void wh_kernel(const float* __restrict__ h,
                                                 const float* __restrict__ W,
                                                 unsigned short* __restrict__ whT) {
    int bid  = blockIdx.x;
    int tile = bid & 63;          // N/32
    int bh   = bid >> 6;
    int hh   = bh & (NH - 1);
    int bb   = bh >> 1;

    __shared__ float Wt[FIN * 132];   // [o][f] transposed, stride 132

    int t = threadIdx.x;
    const float* Ws = W + (size_t)hh * FIN * FOUT;
    for (int idx = t; idx < FIN * FOUT; idx += 256) {
        int f = idx >> 7, o = idx & 127;
        Wt[o * 132 + f] = Ws[idx];
    }
    __syncthreads();

    int o    = t & 127;
    int rg   = t >> 7;
    int row0 = tile * 32 + rg * 16;

    float acc[16];
#pragma unroll
    for (int k = 0; k < 16; ++k) acc[k] = 0.f;

    const float* hb = h + (size_t)bb * Nv * FIN;
    for (int f4 = 0; f4 < FIN; f4 += 4) {
        float4 w4 = *(const float4*)&Wt[o * 132 + f4];
#pragma unroll
        for (int k = 0; k < 16; ++k) {
            float4 h4 = *(const float4*)&hb[(size_t)(row0 + k) * FIN + f4];
            acc[k] += h4.x * w4.x + h4.y * w4.y + h4.z * w4.z + h4.w * w4.w;
        }
    }
    unsigned int us[16];
#pragma unroll
    for (int k = 0; k < 16; ++k) us[k] = f2bf(acc[k]);
    uint4 w0, w1;
    w0.x = us[0] | (us[1] << 16);  w0.y = us[2] | (us[3] << 16);
    w0.z = us[4] | (us[5] << 16);  w0.w = us[6] | (us[7] << 16);
    w1.x = us[8] | (us[9] << 16);  w1.y = us[10] | (us[11] << 16);
    w1.z = us[12] | (us[13] << 16); w1.w = us[14] | (us[15] << 16);
    unsigned short* dst = whT + ((size_t)(bb * NH + hh) * FOUT + o) * Nv + row0;
    *(uint4*)dst       = w0;
    *(uint4*)(dst + 8) = w1;
}

// ---------------- Kernel 3: fused masked-softmax(e) @ Wh via MFMA ----------------
// 512 blocks (b pinned per XCD), 256 threads = 4 waves.
// Wave w: head = w>>1, col-half = (w&1)*64. 32 i-rows per block, j-tile = 64.
// A-frag gen layout: row = lane&15 (+16*rt), k = (lane>>4)*8 + i (+32*kt).
// C/D layout: col = lane&15, row = (lane>>4)*4 + reg  [m89-verified].
__global__ __launch_bounds__(256, 2) void gat_attn_kernel(
    const int* __restrict__ adj, const unsigned short* __restrict__ whT,
    const float* __restrict__ si, const float* __restrict__ sj,
    float* __restrict__ out) {
    int bid   = blockIdx.x;
    int bb    = bid & 7;        // batch pinned to XCD (dispatch round-robins bid%8)
    int itile = bid >> 3;

    int t       = threadIdx.x;
    int w       = t >> 6;
    int l       = t & 63;
    int h       = w >> 1;
    int colbase = (w & 1) << 6;
    int lo16    = l & 15;
    int grp     = l >> 4;

    __shared__ float alpha_lds[2][NH][32];
    __shared__ float linv_lds[NH][32];

    int row0 = itile * 32;
    float sir[2];
    const int* adjr[2];
#pragma unroll
    for (int rt = 0; rt < 2; ++rt) {
        int r = row0 + rt * 16 + lo16;
        sir[rt] = si[(size_t)(bb * NH + h) * Nv + r];
        adjr[rt] = adj + ((size_t)bb * Nv + r) * Nv;
    }
    const float* sjb = sj + (size_t)(bb * NH + h) * Nv;
    const unsigned short* whb = whT + (size_t)(bb * NH + h) * FOUT * Nv;  // [o][n]

    float mrow[2] = {-1e30f, -1e30f};
    float lrow[2] = {0.f, 0.f};
    f32x4 acc[2][4];
#pragma unroll
    for (int rt = 0; rt < 2; ++rt)
#pragma unroll
        for (int ct = 0; ct < 4; ++ct)
            acc[rt][ct] = (f32x4){0.f, 0.f, 0.f, 0.f};

    for (int jt = 0; jt < Nv / 64; ++jt) {
        int jb = jt * 64;
        // ---- loads: adj (2 rows x 16 j) + sj (16 j) per lane ----
        int4   av[2][2][2];
        float4 sv[2][2];
#pragma unroll
        for (int kt = 0; kt < 2; ++kt) {
            int j = jb + kt * 32 + grp * 8;
            sv[kt][0] = *(const float4*)&sjb[j];
            sv[kt][1] = *(const float4*)&sjb[j + 4];
#pragma unroll
            for (int rt = 0; rt < 2; ++rt) {
                av[rt][kt][0] = *(const int4*)&adjr[rt][j];
                av[rt][kt][1] = *(const int4*)&adjr[rt][j + 4];
            }
        }
        // ---- scores e = mask(lrelu(si+sj)) in A-frag layout ----
        float e[2][2][8];
        float tmax[2] = {-1e30f, -1e30f};
#pragma unroll
        for (int rt = 0; rt < 2; ++rt) {
#pragma unroll
            for (int kt = 0; kt < 2; ++kt) {
#pragma unroll
                for (int hf = 0; hf < 2; ++hf) {
                    int4   a4 = av[rt][kt][hf];
                    float4 s4 = sv[kt][hf];
                    float x0 = sir[rt] + s4.x; x0 = fmaxf(x0, 0.2f * x0); x0 = a4.x ? x0 : -INFINITY;
                    float x1 = sir[rt] + s4.y; x1 = fmaxf(x1, 0.2f * x1); x1 = a4.y ? x1 : -INFINITY;
                    float x2 = sir[rt] + s4.z; x2 = fmaxf(x2, 0.2f * x2); x2 = a4.z ? x2 : -INFINITY;
                    float x3 = sir[rt] + s4.w; x3 = fmaxf(x3, 0.2f * x3); x3 = a4.w ? x3 : -INFINITY;
                    e[rt][kt][hf * 4 + 0] = x0;
                    e[rt][kt][hf * 4 + 1] = x1;
                    e[rt][kt][hf * 4 + 2] = x2;
                    e[rt][kt][hf * 4 + 3] = x3;
                    tmax[rt] = fmaxf(tmax[rt], fmaxf(fmaxf(x0, x1), fmaxf(x2, x3)));
                }
            }
        }
#pragma unroll
        for (int rt = 0; rt < 2; ++rt) {
            tmax[rt] = fmaxf(tmax[rt], __shfl_xor(tmax[rt], 16, 64));
            tmax[rt] = fmaxf(tmax[rt], __shfl_xor(tmax[rt], 32, 64));
        }
        // ---- online softmax: p in bf16 A-frags ----
        float alf[2];
        short8 af[2][2];
#pragma unroll
        for (int rt = 0; rt < 2; ++rt) {
            float mnew = fmaxf(mrow[rt], tmax[rt]);
            alf[rt] = __expf(mrow[rt] - mnew);
            mrow[rt] = mnew;
            float ps = 0.f;
#pragma unroll
            for (int kt = 0; kt < 2; ++kt) {
#pragma unroll
                for (int i = 0; i < 8; ++i) {
                    float pv = __expf(e[rt][kt][i] - mnew);
                    ps += pv;
                    af[rt][kt][i] = (short)f2bf(pv);
                }
            }
            ps += __shfl_xor(ps, 16, 64);
            ps += __shfl_xor(ps, 32, 64);
            lrow[rt] = lrow[rt] * alf[rt] + ps;
        }
        // ---- publish alpha (softmax-row layout -> C-row layout) ----
        if (((w & 1) == 0) && l < 32)
            alpha_lds[jt & 1][h][l] = (l < 16) ? alf[0] : alf[1];
        __syncthreads();
        float alr[2][4];
#pragma unroll
        for (int rt = 0; rt < 2; ++rt)
#pragma unroll
            for (int reg = 0; reg < 4; ++reg)
                alr[rt][reg] = alpha_lds[jt & 1][h][rt * 16 + grp * 4 + reg];
#pragma unroll
        for (int rt = 0; rt < 2; ++rt)
#pragma unroll
            for (int ct = 0; ct < 4; ++ct)
#pragma unroll
                for (int reg = 0; reg < 4; ++reg)
                    acc[rt][ct][reg] *= alr[rt][reg];
        // ---- PV: acc += P(16x32) x WhT(32x16), B-frag = contiguous 16B from WhT[o][j] ----
#pragma unroll
        for (int ct = 0; ct < 4; ++ct) {
            const unsigned short* bp = whb + (size_t)(colbase + ct * 16 + lo16) * Nv + jb + grp * 8;
            short8 b0 = *(const short8*)bp;
            short8 b1 = *(const short8*)(bp + 32);
#pragma unroll
            for (int rt = 0; rt < 2; ++rt) {
                acc[rt][ct] = __builtin_amdgcn_mfma_f32_16x16x32_bf16(af[rt][0], b0, acc[rt][ct], 0, 0, 0);
                acc[rt][ct] = __builtin_amdgcn_mfma_f32_16x16x32_bf16(af[rt][1], b1, acc[rt][ct], 0, 0, 0);
            }
        }
    }
    // ---- epilogue: divide by l, store ----
    if (((w & 1) == 0) && l < 32)
        linv_lds[h][l] = 1.0f / ((l < 16) ? lrow[0] : lrow[1]);
    __syncthreads();
#pragma unroll
    for (int rt = 0; rt < 2; ++rt) {
#pragma unroll
        for (int reg = 0; reg < 4; ++reg) {
            float li  = linv_lds[h][rt * 16 + grp * 4 + reg];
            int   row = row0 + rt * 16 + grp * 4 + reg;
            float* op = out + ((size_t)bb * Nv + row) * (NH * FOUT) + h * FOUT + colbase;
#pragma unroll
            for (int ct = 0; ct < 4; ++ct)
                op[ct * 16 + lo16] = acc[rt][ct][reg] * li;
        }
    }
}

extern "C" void kernel_launch(void* const* d_in, const int* in_sizes, int n_in,
                              void* d_out, int out_size, void* d_ws, size_t ws_size,
                              hipStream_t stream) {
    const float* h   = (const float*)d_in[0];
    const int*   adj = (const int*)d_in[1];
    const float* W   = (const float*)d_in[2];
    const float* a   = (const float*)d_in[3];
    float*       out = (float*)d_out;

    unsigned short* whT = (unsigned short*)d_ws;                       // 8 MB bf16 Wh^T
    float* fws = (float*)((char*)d_ws + (size_t)Bv * NH * FOUT * Nv * 2);
    float* si  = fws;                                                  // B*H*N
    float* sj  = si + (size_t)Bv * NH * Nv;
    float* wa  = sj + (size_t)Bv * NH * Nv;                            // H*2*FIN

    wa_kernel  <<<dim3(1),                 dim3(256), 0, stream>>>(W, a, wa);
    sij_kernel <<<dim3(Bv * Nv / 4),       dim3(256), 0, stream>>>(h, wa, si, sj);
    wh_kernel  <<<dim3(Bv * NH * (Nv/32)), dim3(256), 0, stream>>>(h, W, whT);
    gat_attn_kernel<<<dim3(Bv * (Nv/32)),  dim3(256), 0, stream>>>(adj, whT, si, sj, out);
}

// Round 3
// 182.065 us; speedup vs baseline: 3.6362x; 1.2831x over previous
//
#include <hip/hip_runtime.h>
#include <math.h>

constexpr int Bv   = 8;
constexpr int Nv   = 2048;
constexpr int FIN  = 128;
constexpr int FOUT = 128;
constexpr int NH   = 2;
constexpr float LOG2E = 1.44269504088896340736f;

typedef __attribute__((ext_vector_type(8))) short  short8;
typedef __attribute__((ext_vector_type(4))) float  f32x4;

static __device__ __forceinline__ unsigned short f2bf(float f) {
    unsigned u = __builtin_bit_cast(unsigned, f);
    u += 0x7fffu + ((u >> 16) & 1u);          // round-to-nearest-even
    return (unsigned short)(u >> 16);
}
static __device__ __forceinline__ float bf2f(unsigned short s) {
    unsigned u = ((unsigned)s) << 16;
    return __builtin_bit_cast(float, u);
}
static __device__ __forceinline__ float fast_exp2(float x) {
#if __has_builtin(__builtin_amdgcn_exp2f)
    return __builtin_amdgcn_exp2f(x);
#else
    return exp2f(x);
#endif
}

// ---------------- Kernel 0: wa[h][q][f] = log2e * sum_o W[h][f][o]*a[h][q*FOUT+o] ----------------
// grid 2 (per head), 256 threads: t = f*2 + half, each thread sums 64 o's.
__global__ void wa_kernel(const float* __restrict__ W, const float* __restrict__ a,
                          float* __restrict__ wa) {
    int hh = blockIdx.x;
    int t = threadIdx.x;
    int f = t >> 1, half = t & 1;
    const float* Wr = W + ((size_t)hh * FIN + f) * FOUT + half * 64;
    const float* ar = a + (size_t)hh * 2 * FOUT + half * 64;
    float s1 = 0.f, s2 = 0.f;
    for (int o = 0; o < 64; o += 4) {
        float4 w4 = *(const float4*)&Wr[o];
        s1 += w4.x * ar[o] + w4.y * ar[o + 1] + w4.z * ar[o + 2] + w4.w * ar[o + 3];
        s2 += w4.x * ar[FOUT + o] + w4.y * ar[FOUT + o + 1] + w4.z * ar[FOUT + o + 2] + w4.w * ar[FOUT + o + 3];
    }
    s1 += __shfl_xor(s1, 1, 64);
    s2 += __shfl_xor(s2, 1, 64);
    if (half == 0) {
        wa[(hh * 2 + 0) * FIN + f] = s1 * LOG2E;   // fold exp2-domain scale in here
        wa[(hh * 2 + 1) * FIN + f] = s2 * LOG2E;
    }
}

// ---------------- Kernel 1: si/sj[b,h,n] = h[b,n,:] . wa[h][q][:] (log2 domain) ----------------
__global__ __launch_bounds__(256) void sij_kernel(const float* __restrict__ h,
                                                  const float* __restrict__ wa,
                                                  float* __restrict__ si,
                                                  float* __restrict__ sj) {
    int row  = blockIdx.x * 4 + (threadIdx.x >> 6);   // b*N + n
    int lane = threadIdx.x & 63;
    float x0 = h[(size_t)row * FIN + lane];
    float x1 = h[(size_t)row * FIN + 64 + lane];
    float s[4];
#pragma unroll
    for (int q = 0; q < 4; ++q) {
        const float* w = wa + q * FIN;
        s[q] = x0 * w[lane] + x1 * w[64 + lane];
    }
#pragma unroll
    for (int m = 32; m >= 1; m >>= 1) {
#pragma unroll
        for (int q = 0; q < 4; ++q) s[q] += __shfl_xor(s[q], m, 64);
    }
    if (lane == 0) {
        int bb = row >> 11, n = row & (Nv - 1);
        si[((size_t)(bb * NH + 0)) * Nv + n] = s[0];
        sj[((size_t)(bb * NH + 0)) * Nv + n] = s[1];
        si[((size_t)(bb * NH + 1)) * Nv + n] = s[2];
        sj[((size_t)(bb * NH + 1)) * Nv + n] = s[3];
    }
}

// ---------------- Kernel 2: WhT[b,h,o,n] bf16 via MFMA with hi/lo split (fp32-accurate) ----------------
// grid 512: bb = bid&7 (XCD-pinned), hh = (bid>>3)&1, n-tile of 64 = bid>>4.
// 4 waves: wave w owns o in [w*32, w*32+32).
__global__ __launch_bounds__(256, 2) void wh_kernel(const float* __restrict__ h,
                                                    const float* __restrict__ W,
                                                    unsigned short* __restrict__ whT) {
    int bid = blockIdx.x;
    int bb  = bid & 7;
    int r   = bid >> 3;
    int hh  = r & 1;
    int n0  = (r >> 1) * 64;

    __shared__ unsigned short Whi[FIN * 132];   // [o][f], pad 132: conflict-free b128 reads
    __shared__ unsigned short Wlo[FIN * 132];

    int t = threadIdx.x;
    const float* Ws = W + (size_t)hh * FIN * FOUT;
    for (int idx = t; idx < FIN * FOUT; idx += 256) {
        int f = idx >> 7, o = idx & 127;
        float wv = Ws[idx];
        unsigned short uh = f2bf(wv);
        Whi[o * 132 + f] = uh;
        Wlo[o * 132 + f] = f2bf(wv - bf2f(uh));
    }
    __syncthreads();

    int w = t >> 6, l = t & 63, lo16 = l & 15, grp = l >> 4;
    int o0 = w * 32;

    short8 ahi[2][4], alo[2][4];
#pragma unroll
    for (int ot = 0; ot < 2; ++ot)
#pragma unroll
        for (int kt = 0; kt < 4; ++kt) {
            int off = (o0 + ot * 16 + lo16) * 132 + kt * 32 + grp * 8;
            ahi[ot][kt] = *(const short8*)&Whi[off];
            alo[ot][kt] = *(const short8*)&Wlo[off];
        }

    f32x4 acc[2][4];
#pragma unroll
    for (int ot = 0; ot < 2; ++ot)
#pragma unroll
        for (int nt = 0; nt < 4; ++nt) acc[ot][nt] = (f32x4){0.f, 0.f, 0.f, 0.f};

    const float* hb = h + ((size_t)bb * Nv + n0) * FIN;
#pragma unroll
    for (int nt = 0; nt < 4; ++nt) {
#pragma unroll
        for (int kt = 0; kt < 4; ++kt) {
            const float* hp = hb + (size_t)(nt * 16 + lo16) * FIN + kt * 32 + grp * 8;
            float4 x0 = *(const float4*)hp;
            float4 x1 = *(const float4*)(hp + 4);
            float xs[8] = {x0.x, x0.y, x0.z, x0.w, x1.x, x1.y, x1.z, x1.w};
            short8 bhi, blo;
#pragma unroll
            for (int i = 0; i < 8; ++i) {
                unsigned short uh = f2bf(xs[i]);
                bhi[i] = (short)uh;
                blo[i] = (short)f2bf(xs[i] - bf2f(uh));
            }
#pragma unroll
            for (int ot = 0; ot < 2; ++ot) {
                acc[ot][nt] = __builtin_amdgcn_mfma_f32_16x16x32_bf16(ahi[ot][kt], bhi, acc[ot][nt], 0, 0, 0);
                acc[ot][nt] = __builtin_amdgcn_mfma_f32_16x16x32_bf16(ahi[ot][kt], blo, acc[ot][nt], 0, 0, 0);
                acc[ot][nt] = __builtin_amdgcn_mfma_f32_16x16x32_bf16(alo[ot][kt], bhi, acc[ot][nt], 0, 0, 0);
            }
        }
    }
    unsigned short* dst = whT + (size_t)(bb * NH + hh) * FOUT * Nv;
#pragma unroll
    for (int ot = 0; ot < 2; ++ot)
#pragma unroll
        for (int nt = 0; nt < 4; ++nt)
#pragma unroll
            for (int reg = 0; reg < 4; ++reg) {
                int o = o0 + ot * 16 + grp * 4 + reg;
                int n = n0 + nt * 16 + lo16;
                dst[(size_t)o * Nv + n] = f2bf(acc[ot][nt][reg]);
            }
}

// ---------------- Kernel 3: fused masked-softmax(e) @ Wh via MFMA, no online max ----------------
// Scores bounded (|si+sj| <~ 15) => exp2 can't overflow; max-subtraction cancels in p/l. No barriers.
// grid 512: bb = bid&7, itile = bid>>3. 4 waves: (head = w>>1, row-half = w&1), each owns all 128 cols.
__global__ __launch_bounds__(256, 2) void gat_attn_kernel(
    const int* __restrict__ adj, const unsigned short* __restrict__ whT,
    const float* __restrict__ si, const float* __restrict__ sj,
    float* __restrict__ out) {
    int bid   = blockIdx.x;
    int bb    = bid & 7;
    int itile = bid >> 3;

    int t = threadIdx.x;
    int w = t >> 6, l = t & 63, lo16 = l & 15, grp = l >> 4;
    int h = w >> 1, rh = w & 1;
    int r0 = itile * 32 + rh * 16;
    int myrow = r0 + lo16;

    float sir = si[(size_t)(bb * NH + h) * Nv + myrow];
    const int*            adjr = adj + ((size_t)bb * Nv + myrow) * Nv;
    const float*          sjb  = sj + (size_t)(bb * NH + h) * Nv;
    const unsigned short* whb  = whT + (size_t)(bb * NH + h) * FOUT * Nv;

    f32x4 acc[8];
#pragma unroll
    for (int ct = 0; ct < 8; ++ct) acc[ct] = (f32x4){0.f, 0.f, 0.f, 0.f};
    float lrow = 0.f;

    int4   av0[2][2], av1[2][2];
    float4 sv0[2][2], sv1[2][2];

    auto ld = [&](int4 (&av)[2][2], float4 (&sv)[2][2], int jb) {
#pragma unroll
        for (int kt = 0; kt < 2; ++kt) {
            int j = jb + kt * 32 + grp * 8;
            av[kt][0] = *(const int4*)&adjr[j];
            av[kt][1] = *(const int4*)&adjr[j + 4];
            sv[kt][0] = *(const float4*)&sjb[j];
            sv[kt][1] = *(const float4*)&sjb[j + 4];
        }
    };
    ld(av0, sv0, 0);

    auto body = [&](int4 (&avc)[2][2], float4 (&svc)[2][2],
                    int4 (&avn)[2][2], float4 (&svn)[2][2], int jt) {
        int jb = jt * 64;
        if (jt < 31) ld(avn, svn, jb + 64);      // HBM prefetch one tile ahead
        // B-frags from L2-resident WhT (issued before the score VALU stretch)
        short8 bfrag[8][2];
#pragma unroll
        for (int ct = 0; ct < 8; ++ct) {
            const unsigned short* bp = whb + (size_t)(ct * 16 + lo16) * Nv + jb + grp * 8;
            bfrag[ct][0] = *(const short8*)bp;
            bfrag[ct][1] = *(const short8*)(bp + 32);
        }
        // scores -> p = exp2(lrelu2(si+sj)) masked, packed to bf16 A-frags
        short8 af[2];
#pragma unroll
        for (int kt = 0; kt < 2; ++kt) {
#pragma unroll
            for (int hf = 0; hf < 2; ++hf) {
                int4   a4 = avc[kt][hf];
                float4 s4 = svc[kt][hf];
                float x0 = sir + s4.x, x1 = sir + s4.y, x2 = sir + s4.z, x3 = sir + s4.w;
                x0 = fmaxf(x0, 0.2f * x0); x1 = fmaxf(x1, 0.2f * x1);
                x2 = fmaxf(x2, 0.2f * x2); x3 = fmaxf(x3, 0.2f * x3);
                float p0 = fast_exp2(x0), p1 = fast_exp2(x1);
                float p2 = fast_exp2(x2), p3 = fast_exp2(x3);
                p0 = a4.x ? p0 : 0.f; p1 = a4.y ? p1 : 0.f;
                p2 = a4.z ? p2 : 0.f; p3 = a4.w ? p3 : 0.f;
                lrow += (p0 + p1) + (p2 + p3);
                af[kt][hf * 4 + 0] = (short)f2bf(p0);
                af[kt][hf * 4 + 1] = (short)f2bf(p1);
                af[kt][hf * 4 + 2] = (short)f2bf(p2);
                af[kt][hf * 4 + 3] = (short)f2bf(p3);
            }
        }
        // PV
#pragma unroll
        for (int ct = 0; ct < 8; ++ct) {
            acc[ct] = __builtin_amdgcn_mfma_f32_16x16x32_bf16(af[0], bfrag[ct][0], acc[ct], 0, 0, 0);
            acc[ct] = __builtin_amdgcn_mfma_f32_16x16x32_bf16(af[1], bfrag[ct][1], acc[ct], 0, 0, 0);
        }
    };

    for (int jt = 0; jt < 32; jt += 2) {
        body(av0, sv0, av1, sv1, jt);
        body(av1, sv1, av0, sv0, jt + 1);
    }

    // epilogue: row sums live per lo16; reduce across grps, redistribute to C-rows
    lrow += __shfl_xor(lrow, 16, 64);
    lrow += __shfl_xor(lrow, 32, 64);
    float linv = 1.0f / lrow;
    float lr[4];
#pragma unroll
    for (int reg = 0; reg < 4; ++reg) lr[reg] = __shfl(linv, grp * 4 + reg, 64);
#pragma unroll
    for (int reg = 0; reg < 4; ++reg) {
        int row = r0 + grp * 4 + reg;
        float* op = out + ((size_t)(bb * Nv + row)) * (NH * FOUT) + h * FOUT;
#pragma unroll
        for (int ct = 0; ct < 8; ++ct)
            op[ct * 16 + lo16] = acc[ct][reg] * lr[reg];
    }
}

extern "C" void kernel_launch(void* const* d_in, const int* in_sizes, int n_in,
                              void* d_out, int out_size, void* d_ws, size_t ws_size,
                              hipStream_t stream) {
    const float* h   = (const float*)d_in[0];
    const int*   adj = (const int*)d_in[1];
    const float* W   = (const float*)d_in[2];
    const float* a   = (const float*)d_in[3];
    float*       out = (float*)d_out;

    unsigned short* whT = (unsigned short*)d_ws;                       // 8 MB bf16 Wh^T
    float* fws = (float*)((char*)d_ws + (size_t)Bv * NH * FOUT * Nv * 2);
    float* si  = fws;
    float* sj  = si + (size_t)Bv * NH * Nv;
    float* wa  = sj + (size_t)Bv * NH * Nv;

    wa_kernel <<<dim3(2),               dim3(256), 0, stream>>>(W, a, wa);
    sij_kernel<<<dim3(Bv * Nv / 4),     dim3(256), 0, stream>>>(h, wa, si, sj);
    wh_kernel <<<dim3(Bv * NH * (Nv/64)), dim3(256), 0, stream>>>(h, W, whT);
    gat_attn_kernel<<<dim3(Bv * (Nv/32)), dim3(256), 0, stream>>>(adj, whT, si, sj, out);
}

// Round 4
// 113.636 us; speedup vs baseline: 5.8257x; 1.6022x over previous
//
#include <hip/hip_runtime.h>
#include <math.h>

constexpr int Bv   = 8;
constexpr int Nv   = 2048;
constexpr int FIN  = 128;
constexpr int FOUT = 128;
constexpr int NH   = 2;
constexpr float LOG2E = 1.44269504088896340736f;

typedef __attribute__((ext_vector_type(8))) short  short8;
typedef __attribute__((ext_vector_type(4))) float  f32x4;
typedef __attribute__((ext_vector_type(4))) int    i32x4;

static __device__ __forceinline__ unsigned short f2bf(float f) {
    unsigned u = __builtin_bit_cast(unsigned, f);
    u += 0x7fffu + ((u >> 16) & 1u);          // round-to-nearest-even
    return (unsigned short)(u >> 16);
}
static __device__ __forceinline__ float bf2f(unsigned short s) {
    unsigned u = ((unsigned)s) << 16;
    return __builtin_bit_cast(float, u);
}
static __device__ __forceinline__ float fast_exp2(float x) {
#if __has_builtin(__builtin_amdgcn_exp2f)
    return __builtin_amdgcn_exp2f(x);
#else
    return exp2f(x);
#endif
}
static __device__ __forceinline__ unsigned cvt_pk_bf16(float lo, float hi) {
    unsigned r;
    asm("v_cvt_pk_bf16_f32 %0, %1, %2" : "=v"(r) : "v"(lo), "v"(hi));
    return r;
}

// ---------------- Kernel 0: wa[h][q][f] = log2e * sum_o W[h][f][o]*a[h][q*FOUT+o] ----------------
__global__ void wa_kernel(const float* __restrict__ W, const float* __restrict__ a,
                          float* __restrict__ wa) {
    int hh = blockIdx.x;
    int t = threadIdx.x;
    int f = t >> 1, half = t & 1;
    const float* Wr = W + ((size_t)hh * FIN + f) * FOUT + half * 64;
    const float* ar = a + (size_t)hh * 2 * FOUT + half * 64;
    float s1 = 0.f, s2 = 0.f;
    for (int o = 0; o < 64; o += 4) {
        float4 w4 = *(const float4*)&Wr[o];
        s1 += w4.x * ar[o] + w4.y * ar[o + 1] + w4.z * ar[o + 2] + w4.w * ar[o + 3];
        s2 += w4.x * ar[FOUT + o] + w4.y * ar[FOUT + o + 1] + w4.z * ar[FOUT + o + 2] + w4.w * ar[FOUT + o + 3];
    }
    s1 += __shfl_xor(s1, 1, 64);
    s2 += __shfl_xor(s2, 1, 64);
    if (half == 0) {
        wa[(hh * 2 + 0) * FIN + f] = s1 * LOG2E;
        wa[(hh * 2 + 1) * FIN + f] = s2 * LOG2E;
    }
}

// ---------------- Kernel 1: si/sj[b,h,n] = h[b,n,:] . wa[h][q][:] (log2 domain) ----------------
__global__ __launch_bounds__(256) void sij_kernel(const float* __restrict__ h,
                                                  const float* __restrict__ wa,
                                                  float* __restrict__ si,
                                                  float* __restrict__ sj) {
    int row  = blockIdx.x * 4 + (threadIdx.x >> 6);   // b*N + n
    int lane = threadIdx.x & 63;
    float x0 = h[(size_t)row * FIN + lane];
    float x1 = h[(size_t)row * FIN + 64 + lane];
    float s[4];
#pragma unroll
    for (int q = 0; q < 4; ++q) {
        const float* w = wa + q * FIN;
        s[q] = x0 * w[lane] + x1 * w[64 + lane];
    }
#pragma unroll
    for (int m = 32; m >= 1; m >>= 1) {
#pragma unroll
        for (int q = 0; q < 4; ++q) s[q] += __shfl_xor(s[q], m, 64);
    }
    if (lane == 0) {
        int bb = row >> 11, n = row & (Nv - 1);
        si[((size_t)(bb * NH + 0)) * Nv + n] = s[0];
        sj[((size_t)(bb * NH + 0)) * Nv + n] = s[1];
        si[((size_t)(bb * NH + 1)) * Nv + n] = s[2];
        sj[((size_t)(bb * NH + 1)) * Nv + n] = s[3];
    }
}

// ---------------- Kernel 1b: pack adj rows into 64-bit masks ----------------
// adjp[b][jt][n] = bits j in [jt*64, jt*64+64) of row n. One wave per (b, jt, 32-row block).
__global__ __launch_bounds__(256) void pack_kernel(const int* __restrict__ adj,
                                                   unsigned long long* __restrict__ adjp) {
    int wid = blockIdx.x * 4 + (threadIdx.x >> 6);   // 0..16383
    int l   = threadIdx.x & 63;
    int b   = wid >> 11;
    int r5  = wid & 2047;
    int jt  = r5 >> 6;         // 32
    int rb  = r5 & 63;         // 64 row-blocks of 32
    const int* src = adj + ((size_t)b * Nv + rb * 32) * Nv + jt * 64 + l;
    unsigned long long* dst = adjp + ((size_t)b * 32 + jt) * Nv + rb * 32;
    for (int r = 0; r < 32; r += 4) {
        int a0 = src[(size_t)(r + 0) * Nv];
        int a1 = src[(size_t)(r + 1) * Nv];
        int a2 = src[(size_t)(r + 2) * Nv];
        int a3 = src[(size_t)(r + 3) * Nv];
        unsigned long long b0 = __ballot(a0 != 0);
        unsigned long long b1 = __ballot(a1 != 0);
        unsigned long long b2 = __ballot(a2 != 0);
        unsigned long long b3 = __ballot(a3 != 0);
        if (l == 0) {
            uint4 q0 = {(unsigned)b0, (unsigned)(b0 >> 32), (unsigned)b1, (unsigned)(b1 >> 32)};
            uint4 q1 = {(unsigned)b2, (unsigned)(b2 >> 32), (unsigned)b3, (unsigned)(b3 >> 32)};
            *(uint4*)&dst[r]     = q0;
            *(uint4*)&dst[r + 2] = q1;
        }
    }
}

// ---------------- Kernel 2: Wh in MFMA-B-fragment-major layout (bf16, hi/lo split fp32-accurate) ----
// whf flat index: ((((bh*32 + jt)*8 + ct)*2 + kt)*64 + lane)*8 + i
//   where for element (o, n): jt=n>>6, r=n&63, kt=r>>5, gf=(r>>3)&3, i=r&7, ct=o>>4, lane=gf*16+(o&15)
__global__ __launch_bounds__(256, 2) void wh_kernel(const float* __restrict__ h,
                                                    const float* __restrict__ W,
                                                    unsigned short* __restrict__ whf) {
    int bid = blockIdx.x;
    int bb  = bid & 7;
    int r   = bid >> 3;
    int hh  = r & 1;
    int n0  = (r >> 1) * 64;
    int jtb = n0 >> 6;

    __shared__ unsigned short Whi[FIN * 132];
    __shared__ unsigned short Wlo[FIN * 132];

    int t = threadIdx.x;
    const float* Ws = W + (size_t)hh * FIN * FOUT;
    for (int idx = t; idx < FIN * FOUT; idx += 256) {
        int f = idx >> 7, o = idx & 127;
        float wv = Ws[idx];
        unsigned short uh = f2bf(wv);
        Whi[o * 132 + f] = uh;
        Wlo[o * 132 + f] = f2bf(wv - bf2f(uh));
    }
    __syncthreads();

    int w = t >> 6, l = t & 63, lo16 = l & 15, grp = l >> 4;
    int o0 = w * 32;

    short8 ahi[2][4], alo[2][4];
#pragma unroll
    for (int ot = 0; ot < 2; ++ot)
#pragma unroll
        for (int kt = 0; kt < 4; ++kt) {
            int off = (o0 + ot * 16 + lo16) * 132 + kt * 32 + grp * 8;
            ahi[ot][kt] = *(const short8*)&Whi[off];
            alo[ot][kt] = *(const short8*)&Wlo[off];
        }

    f32x4 acc[2][4];
#pragma unroll
    for (int ot = 0; ot < 2; ++ot)
#pragma unroll
        for (int nt = 0; nt < 4; ++nt) acc[ot][nt] = (f32x4){0.f, 0.f, 0.f, 0.f};

    const float* hb = h + ((size_t)bb * Nv + n0) * FIN;
#pragma unroll
    for (int nt = 0; nt < 4; ++nt) {
#pragma unroll
        for (int kt = 0; kt < 4; ++kt) {
            const float* hp = hb + (size_t)(nt * 16 + lo16) * FIN + kt * 32 + grp * 8;
            float4 x0 = *(const float4*)hp;
            float4 x1 = *(const float4*)(hp + 4);
            float xs[8] = {x0.x, x0.y, x0.z, x0.w, x1.x, x1.y, x1.z, x1.w};
            short8 bhi, blo;
#pragma unroll
            for (int i = 0; i < 8; ++i) {
                unsigned short uh = f2bf(xs[i]);
                bhi[i] = (short)uh;
                blo[i] = (short)f2bf(xs[i] - bf2f(uh));
            }
#pragma unroll
            for (int ot = 0; ot < 2; ++ot) {
                acc[ot][nt] = __builtin_amdgcn_mfma_f32_16x16x32_bf16(ahi[ot][kt], bhi, acc[ot][nt], 0, 0, 0);
                acc[ot][nt] = __builtin_amdgcn_mfma_f32_16x16x32_bf16(ahi[ot][kt], blo, acc[ot][nt], 0, 0, 0);
                acc[ot][nt] = __builtin_amdgcn_mfma_f32_16x16x32_bf16(alo[ot][kt], bhi, acc[ot][nt], 0, 0, 0);
            }
        }
    }
    unsigned short* db = whf + (size_t)(bb * NH + hh) * 32 * 8192;
#pragma unroll
    for (int ot = 0; ot < 2; ++ot)
#pragma unroll
        for (int nt = 0; nt < 4; ++nt)
#pragma unroll
            for (int reg = 0; reg < 4; ++reg) {
                int o  = o0 + ot * 16 + grp * 4 + reg;
                int n  = nt * 16 + lo16;           // within 64-tile
                int kt = n >> 5, gf = (n >> 3) & 3, i = n & 7;
                int ct = o >> 4, lf = o & 15;
                db[((((size_t)jtb * 8 + ct) * 2 + kt) * 64 + gf * 16 + lf) * 8 + i] =
                    f2bf(acc[ot][nt][reg]);
            }
}

// ---------------- Kernel 3: fused masked-softmax @ Wh, frag-layout B, bitmask adj ----------------
// grid 1024: bb = bid&7 (XCD), itile = (bid>>3)&63, ch = bid>>9 (col half).
// 4 waves: h = w>>1, rh = w&1. Wave: 16 rows x 64 cols x all j. l via all-ones B-frag MFMA.
__global__ __launch_bounds__(256, 4) void gat_attn_kernel(
    const unsigned long long* __restrict__ adjp, const unsigned short* __restrict__ whf,
    const float* __restrict__ si, const float* __restrict__ sj,
    float* __restrict__ out) {
    int bid   = blockIdx.x;
    int bb    = bid & 7;
    int r2    = bid >> 3;
    int itile = r2 & 63;
    int ch    = r2 >> 6;

    int t = threadIdx.x;
    int w = t >> 6, l = t & 63, lo16 = l & 15, grp = l >> 4;
    int h = w >> 1, rh = w & 1;
    int r0 = itile * 32 + rh * 16;
    int myrow = r0 + lo16;

    float sir = si[(size_t)(bb * NH + h) * Nv + myrow];
    const unsigned long long* adjr = adjp + (size_t)bb * 32 * Nv + myrow;   // +jt*Nv
    const float*          sjb = sj + (size_t)(bb * NH + h) * Nv;
    const unsigned short* wb  = whf + (size_t)(bb * NH + h) * 32 * 8192 + ch * 4096;

    f32x4 acc[4], accL;
#pragma unroll
    for (int ct = 0; ct < 4; ++ct) acc[ct] = (f32x4){0.f, 0.f, 0.f, 0.f};
    accL = (f32x4){0.f, 0.f, 0.f, 0.f};

    const int ones_w = 0x3f803f80;                  // two bf16 1.0
    short8 onesf = __builtin_bit_cast(short8, (i32x4){ones_w, ones_w, ones_w, ones_w});

    unsigned long long m0, m1;
    float4 sv0[2][2], sv1[2][2];

    auto ldmeta = [&](unsigned long long& m, float4 (&sv)[2][2], int jt) {
        m = adjr[(size_t)jt * Nv];
        int jb = jt * 64;
#pragma unroll
        for (int kt = 0; kt < 2; ++kt) {
            sv[kt][0] = *(const float4*)&sjb[jb + kt * 32 + grp * 8];
            sv[kt][1] = *(const float4*)&sjb[jb + kt * 32 + grp * 8 + 4];
        }
    };
    ldmeta(m0, sv0, 0);

    auto body = [&](unsigned long long& mc, float4 (&svc)[2][2],
                    unsigned long long& mn, float4 (&svn)[2][2], int jt) {
        // B-frags: fully contiguous 1 KB loads (frag-major layout)
        const unsigned short* jbp = wb + (size_t)jt * 8192 + (size_t)l * 8;
        short8 bf[4][2];
#pragma unroll
        for (int ct = 0; ct < 4; ++ct) {
            bf[ct][0] = *(const short8*)(jbp + (ct * 2 + 0) * 512);
            bf[ct][1] = *(const short8*)(jbp + (ct * 2 + 1) * 512);
        }
        if (jt < 31) ldmeta(mn, svn, jt + 1);       // prefetch next tile's mask+sj

        unsigned mw0 = (unsigned)mc, mw1 = (unsigned)(mc >> 32);
        short8 af[2];
#pragma unroll
        for (int kt = 0; kt < 2; ++kt) {
            unsigned mb = ((kt ? mw1 : mw0) >> (grp * 8)) & 0xFFu;
            unsigned ws[4];
#pragma unroll
            for (int hf = 0; hf < 2; ++hf) {
                float4 s4 = svc[kt][hf];
                float x0 = sir + s4.x, x1 = sir + s4.y, x2 = sir + s4.z, x3 = sir + s4.w;
                x0 = fmaxf(x0, 0.2f * x0); x1 = fmaxf(x1, 0.2f * x1);
                x2 = fmaxf(x2, 0.2f * x2); x3 = fmaxf(x3, 0.2f * x3);
                float p0 = fast_exp2(x0), p1 = fast_exp2(x1);
                float p2 = fast_exp2(x2), p3 = fast_exp2(x3);
                p0 = (mb & (1u << (hf * 4 + 0))) ? p0 : 0.f;
                p1 = (mb & (1u << (hf * 4 + 1))) ? p1 : 0.f;
                p2 = (mb & (1u << (hf * 4 + 2))) ? p2 : 0.f;
                p3 = (mb & (1u << (hf * 4 + 3))) ? p3 : 0.f;
                ws[hf * 2 + 0] = cvt_pk_bf16(p0, p1);
                ws[hf * 2 + 1] = cvt_pk_bf16(p2, p3);
            }
            af[kt] = __builtin_bit_cast(short8, (i32x4){(int)ws[0], (int)ws[1], (int)ws[2], (int)ws[3]});
        }
#pragma unroll
        for (int ct = 0; ct < 4; ++ct) {
            acc[ct] = __builtin_amdgcn_mfma_f32_16x16x32_bf16(af[0], bf[ct][0], acc[ct], 0, 0, 0);
            acc[ct] = __builtin_amdgcn_mfma_f32_16x16x32_bf16(af[1], bf[ct][1], acc[ct], 0, 0, 0);
        }
        accL = __builtin_amdgcn_mfma_f32_16x16x32_bf16(af[0], onesf, accL, 0, 0, 0);
        accL = __builtin_amdgcn_mfma_f32_16x16x32_bf16(af[1], onesf, accL, 0, 0, 0);
    };

    for (int jt = 0; jt < 32; jt += 2) {
        body(m0, sv0, m1, sv1, jt);
        body(m1, sv1, m0, sv0, jt + 1);
    }

    // epilogue: accL holds l per C-row (same value in every col); divide and store
#pragma unroll
    for (int reg = 0; reg < 4; ++reg) {
        float linv = 1.0f / accL[reg];
        int   row  = r0 + grp * 4 + reg;
        float* op = out + ((size_t)(bb * Nv + row)) * (NH * FOUT) + h * FOUT + ch * 64;
#pragma unroll
        for (int ct = 0; ct < 4; ++ct)
            op[ct * 16 + lo16] = acc[ct][reg] * linv;
    }
}

extern "C" void kernel_launch(void* const* d_in, const int* in_sizes, int n_in,
                              void* d_out, int out_size, void* d_ws, size_t ws_size,
                              hipStream_t stream) {
    const float* h   = (const float*)d_in[0];
    const int*   adj = (const int*)d_in[1];
    const float* W   = (const float*)d_in[2];
    const float* a   = (const float*)d_in[3];
    float*       out = (float*)d_out;

    char* ws = (char*)d_ws;
    unsigned short*     whf  = (unsigned short*)ws;                    // 8.39 MB
    unsigned long long* adjp = (unsigned long long*)(ws + 8388608);    // 4.19 MB
    float* si = (float*)(ws + 8388608 + 4194304);
    float* sj = si + (size_t)Bv * NH * Nv;
    float* wa = sj + (size_t)Bv * NH * Nv;

    wa_kernel  <<<dim3(2),                  dim3(256), 0, stream>>>(W, a, wa);
    sij_kernel <<<dim3(Bv * Nv / 4),        dim3(256), 0, stream>>>(h, wa, si, sj);
    pack_kernel<<<dim3(4096),               dim3(256), 0, stream>>>(adj, adjp);
    wh_kernel  <<<dim3(Bv * NH * (Nv/64)),  dim3(256), 0, stream>>>(h, W, whf);
    gat_attn_kernel<<<dim3(Bv * (Nv/32) * 2), dim3(256), 0, stream>>>(adjp, whf, si, sj, out);
}

// Round 5
// 105.158 us; speedup vs baseline: 6.2955x; 1.0806x over previous
//
#include <hip/hip_runtime.h>
#include <math.h>

constexpr int Bv   = 8;
constexpr int Nv   = 2048;
constexpr int FIN  = 128;
constexpr int FOUT = 128;
constexpr int NH   = 2;
constexpr float LOG2E = 1.44269504088896340736f;

typedef __attribute__((ext_vector_type(8)))  short short8;
typedef __attribute__((ext_vector_type(4)))  float f32x4;
typedef __attribute__((ext_vector_type(16))) float f32x16;
typedef __attribute__((ext_vector_type(4)))  int   i32x4;
typedef unsigned long long u64;

static __device__ __forceinline__ unsigned short f2bf(float f) {
    unsigned u = __builtin_bit_cast(unsigned, f);
    u += 0x7fffu + ((u >> 16) & 1u);          // round-to-nearest-even
    return (unsigned short)(u >> 16);
}
static __device__ __forceinline__ float bf2f(unsigned short s) {
    unsigned u = ((unsigned)s) << 16;
    return __builtin_bit_cast(float, u);
}
static __device__ __forceinline__ float fast_exp2(float x) {
#if __has_builtin(__builtin_amdgcn_exp2f)
    return __builtin_amdgcn_exp2f(x);
#else
    return exp2f(x);
#endif
}
static __device__ __forceinline__ unsigned cvt_pk_bf16(float lo, float hi) {
    unsigned r;
    asm("v_cvt_pk_bf16_f32 %0, %1, %2" : "=v"(r) : "v"(lo), "v"(hi));
    return r;
}

// ---------------- Kernel 0: wa[h][q][f] = log2e * sum_o W[h][f][o]*a[h][q*FOUT+o] ----------------
__global__ void wa_kernel(const float* __restrict__ W, const float* __restrict__ a,
                          float* __restrict__ wa) {
    int hh = blockIdx.x;
    int t = threadIdx.x;
    int f = t >> 1, half = t & 1;
    const float* Wr = W + ((size_t)hh * FIN + f) * FOUT + half * 64;
    const float* ar = a + (size_t)hh * 2 * FOUT + half * 64;
    float s1 = 0.f, s2 = 0.f;
    for (int o = 0; o < 64; o += 4) {
        float4 w4 = *(const float4*)&Wr[o];
        s1 += w4.x * ar[o] + w4.y * ar[o + 1] + w4.z * ar[o + 2] + w4.w * ar[o + 3];
        s2 += w4.x * ar[FOUT + o] + w4.y * ar[FOUT + o + 1] + w4.z * ar[FOUT + o + 2] + w4.w * ar[FOUT + o + 3];
    }
    s1 += __shfl_xor(s1, 1, 64);
    s2 += __shfl_xor(s2, 1, 64);
    if (half == 0) {
        wa[(hh * 2 + 0) * FIN + f] = s1 * LOG2E;
        wa[(hh * 2 + 1) * FIN + f] = s2 * LOG2E;
    }
}

// ---------------- Fat prep kernel: pack (0..4095) | sij (4096..8191) | wh (8192..8703) -------------
// All three are independent given wa; fusing overlaps pack's HBM stream with wh's MFMA work.
// whf layout (per b,h): chunk = (jt*4 + kt)*4 + ctq; elem (col o, row n):
//   jt=n>>6, kt=(n>>4)&3, kh=(n>>3)&1, i=n&7, ctq=o>>5; flat = (chunk*64 + kh*32 + (o&31))*8 + i
__global__ __launch_bounds__(256, 2) void prep_kernel(
    const float* __restrict__ h, const float* __restrict__ W,
    const int* __restrict__ adj, const float* __restrict__ wa,
    u64* __restrict__ adjp, unsigned short* __restrict__ whf,
    float* __restrict__ si, float* __restrict__ sj) {
    __shared__ unsigned short Whi[FIN * 132];
    __shared__ unsigned short Wlo[FIN * 132];

    int bid = blockIdx.x;
    int t   = threadIdx.x;

    if (bid < 4096) {
        // ---------------- pack: adjp[b][jt][n] = bitmask of 64 j's ----------------
        int wid = bid * 4 + (t >> 6);
        int l   = t & 63;
        int b   = wid >> 11;
        int r5  = wid & 2047;
        int jt  = r5 >> 6;
        int rb  = r5 & 63;
        const int* src = adj + ((size_t)b * Nv + rb * 32) * Nv + jt * 64 + l;
        u64* dst = adjp + ((size_t)b * 32 + jt) * Nv + rb * 32;
        for (int r = 0; r < 32; r += 8) {
            int av[8];
#pragma unroll
            for (int k = 0; k < 8; ++k) av[k] = src[(size_t)(r + k) * Nv];
            u64 m[8];
#pragma unroll
            for (int k = 0; k < 8; ++k) m[k] = __ballot(av[k] != 0);
            if (l == 0) {
#pragma unroll
                for (int k = 0; k < 8; k += 2) {
                    uint4 q = {(unsigned)m[k], (unsigned)(m[k] >> 32),
                               (unsigned)m[k + 1], (unsigned)(m[k + 1] >> 32)};
                    *(uint4*)&dst[r + k] = q;
                }
            }
        }
    } else if (bid < 8192) {
        // ---------------- sij ----------------
        int row  = (bid - 4096) * 4 + (t >> 6);
        int lane = t & 63;
        float x0 = h[(size_t)row * FIN + lane];
        float x1 = h[(size_t)row * FIN + 64 + lane];
        float s[4];
#pragma unroll
        for (int q = 0; q < 4; ++q) {
            const float* wp = wa + q * FIN;
            s[q] = x0 * wp[lane] + x1 * wp[64 + lane];
        }
#pragma unroll
        for (int m = 32; m >= 1; m >>= 1) {
#pragma unroll
            for (int q = 0; q < 4; ++q) s[q] += __shfl_xor(s[q], m, 64);
        }
        if (lane == 0) {
            int bb = row >> 11, n = row & (Nv - 1);
            si[((size_t)(bb * NH + 0)) * Nv + n] = s[0];
            sj[((size_t)(bb * NH + 0)) * Nv + n] = s[1];
            si[((size_t)(bb * NH + 1)) * Nv + n] = s[2];
            sj[((size_t)(bb * NH + 1)) * Nv + n] = s[3];
        }
    } else {
        // ---------------- wh: Wh bf16 (hi/lo split, fp32-accurate) into frag-major whf ----------
        int wb2 = bid - 8192;          // 0..511
        int bb  = wb2 & 7;
        int r2  = wb2 >> 3;
        int hh  = r2 & 1;
        int jtb = r2 >> 1;             // 64-row tile index
        int n0  = jtb * 64;

        const float* Ws = W + (size_t)hh * FIN * FOUT;
        for (int idx = t; idx < FIN * FOUT; idx += 256) {
            int f = idx >> 7, o = idx & 127;
            float wv = Ws[idx];
            unsigned short uh = f2bf(wv);
            Whi[o * 132 + f] = uh;
            Wlo[o * 132 + f] = f2bf(wv - bf2f(uh));
        }
        __syncthreads();

        int w = t >> 6, l = t & 63, lo16 = l & 15, grp = l >> 4;
        int o0 = w * 32;

        short8 ahi[2][4], alo[2][4];
#pragma unroll
        for (int ot = 0; ot < 2; ++ot)
#pragma unroll
            for (int kt = 0; kt < 4; ++kt) {
                int off = (o0 + ot * 16 + lo16) * 132 + kt * 32 + grp * 8;
                ahi[ot][kt] = *(const short8*)&Whi[off];
                alo[ot][kt] = *(const short8*)&Wlo[off];
            }

        f32x4 acc[2][4];
#pragma unroll
        for (int ot = 0; ot < 2; ++ot)
#pragma unroll
            for (int nt = 0; nt < 4; ++nt) acc[ot][nt] = (f32x4){0.f, 0.f, 0.f, 0.f};

        const float* hb = h + ((size_t)bb * Nv + n0) * FIN;
#pragma unroll
        for (int nt = 0; nt < 4; ++nt) {
#pragma unroll
            for (int kt = 0; kt < 4; ++kt) {
                const float* hp = hb + (size_t)(nt * 16 + lo16) * FIN + kt * 32 + grp * 8;
                float4 x0 = *(const float4*)hp;
                float4 x1 = *(const float4*)(hp + 4);
                float xs[8] = {x0.x, x0.y, x0.z, x0.w, x1.x, x1.y, x1.z, x1.w};
                short8 bhi, blo;
#pragma unroll
                for (int i = 0; i < 8; ++i) {
                    unsigned short uh = f2bf(xs[i]);
                    bhi[i] = (short)uh;
                    blo[i] = (short)f2bf(xs[i] - bf2f(uh));
                }
#pragma unroll
                for (int ot = 0; ot < 2; ++ot) {
                    acc[ot][nt] = __builtin_amdgcn_mfma_f32_16x16x32_bf16(ahi[ot][kt], bhi, acc[ot][nt], 0, 0, 0);
                    acc[ot][nt] = __builtin_amdgcn_mfma_f32_16x16x32_bf16(ahi[ot][kt], blo, acc[ot][nt], 0, 0, 0);
                    acc[ot][nt] = __builtin_amdgcn_mfma_f32_16x16x32_bf16(alo[ot][kt], bhi, acc[ot][nt], 0, 0, 0);
                }
            }
        }
        unsigned short* db = whf + (size_t)(bb * NH + hh) * 262144;
#pragma unroll
        for (int ot = 0; ot < 2; ++ot)
#pragma unroll
            for (int nt = 0; nt < 4; ++nt)
#pragma unroll
                for (int reg = 0; reg < 4; ++reg) {
                    // n = n0 + nt*16 + lo16 -> kt = nt, kh = lo16>>3, i = lo16&7; o = o0+ot*16+grp*4+reg
                    int oc = ot * 16 + grp * 4 + reg;
                    db[(size_t)(((jtb * 4 + nt) * 4 + w) * 64 + (lo16 >> 3) * 32 + oc) * 8 + (lo16 & 7)] =
                        f2bf(acc[ot][nt][reg]);
                }
    }
}

// ---------------- attn: 32x32x16 MFMA, j-split x2, no online max, bitmask adj ----------------
// grid 1024: bb=bid&7 (XCD), rp=(bid>>3)&31 (64-row pair), hh=(bid>>8)&1, ch=bid>>9 (col half).
// 4 waves: jp=w&1 (j-half, 16 tiles each), rw=w>>1 (32-row group). Wave: 32 rows x 64 cols.
// A layout (32x32x16): row=l&31, k=(l>>5)*8+i. C/D: col=l&31, row=(reg&3)+8*(reg>>2)+4*(l>>5).
__global__ __launch_bounds__(256, 3) void gat_attn_kernel(
    const u64* __restrict__ adjp, const unsigned short* __restrict__ whf,
    const float* __restrict__ si, const float* __restrict__ sj,
    float* __restrict__ out) {
    int bid = blockIdx.x;
    int bb  = bid & 7;
    int r2  = bid >> 3;
    int rp  = r2 & 31;
    int hh  = (r2 >> 5) & 1;
    int ch  = r2 >> 6;

    int t = threadIdx.x, w = t >> 6, l = t & 63;
    int jp = w & 1, rw = w >> 1;
    int lo32 = l & 31, kh = l >> 5;
    int r0 = rp * 64 + rw * 32;
    int myrow = r0 + lo32;

    float sir = si[(size_t)(bb * NH + hh) * Nv + myrow];
    const u64*   adjr = adjp + (size_t)bb * 32 * Nv + myrow;
    const float* sjb  = sj + (size_t)(bb * NH + hh) * Nv;
    const unsigned short* wbp = whf + (size_t)(bb * NH + hh) * 262144 + (size_t)l * 8;

    f32x16 acc0, acc1, accL;
#pragma unroll
    for (int i = 0; i < 16; ++i) { acc0[i] = 0.f; acc1[i] = 0.f; accL[i] = 0.f; }

    const int ones_w = 0x3f803f80;
    short8 onesf = __builtin_bit_cast(short8, (i32x4){ones_w, ones_w, ones_w, ones_w});

    int jt0 = jp * 16;
    u64 mask = adjr[(size_t)jt0 * Nv];
    for (int jtl = 0; jtl < 16; ++jtl) {
        int jt = jt0 + jtl;
        int jb = jt * 64;
        // B-frags: contiguous 1 KB/wave loads, L2-resident (frag-major layout)
        const unsigned short* fb = wbp + (size_t)(jt * 16 + ch * 2) * 512;
        short8 bf[4][2];
#pragma unroll
        for (int kt = 0; kt < 4; ++kt) {
            bf[kt][0] = *(const short8*)(fb + (kt * 4 + 0) * 512);
            bf[kt][1] = *(const short8*)(fb + (kt * 4 + 1) * 512);
        }
        u64 mcur = mask;
        if (jtl < 15) mask = adjr[(size_t)(jt + 1) * Nv];

        short8 af[4];
#pragma unroll
        for (int kt = 0; kt < 4; ++kt) {
            unsigned mb = (unsigned)(mcur >> (kt * 16 + kh * 8)) & 0xFFu;
            const float* sp = &sjb[jb + kt * 16 + kh * 8];
            float4 s0 = *(const float4*)sp;
            float4 s1 = *(const float4*)(sp + 4);
            float x0 = sir + s0.x, x1 = sir + s0.y, x2 = sir + s0.z, x3 = sir + s0.w;
            float x4 = sir + s1.x, x5 = sir + s1.y, x6 = sir + s1.z, x7 = sir + s1.w;
            x0 = fmaxf(x0, 0.2f * x0); x1 = fmaxf(x1, 0.2f * x1);
            x2 = fmaxf(x2, 0.2f * x2); x3 = fmaxf(x3, 0.2f * x3);
            x4 = fmaxf(x4, 0.2f * x4); x5 = fmaxf(x5, 0.2f * x5);
            x6 = fmaxf(x6, 0.2f * x6); x7 = fmaxf(x7, 0.2f * x7);
            float p0 = fast_exp2(x0), p1 = fast_exp2(x1), p2 = fast_exp2(x2), p3 = fast_exp2(x3);
            float p4 = fast_exp2(x4), p5 = fast_exp2(x5), p6 = fast_exp2(x6), p7 = fast_exp2(x7);
            p0 = (mb & 1u)   ? p0 : 0.f;  p1 = (mb & 2u)   ? p1 : 0.f;
            p2 = (mb & 4u)   ? p2 : 0.f;  p3 = (mb & 8u)   ? p3 : 0.f;
            p4 = (mb & 16u)  ? p4 : 0.f;  p5 = (mb & 32u)  ? p5 : 0.f;
            p6 = (mb & 64u)  ? p6 : 0.f;  p7 = (mb & 128u) ? p7 : 0.f;
            unsigned w0 = cvt_pk_bf16(p0, p1), w1 = cvt_pk_bf16(p2, p3);
            unsigned w2 = cvt_pk_bf16(p4, p5), w3 = cvt_pk_bf16(p6, p7);
            af[kt] = __builtin_bit_cast(short8, (i32x4){(int)w0, (int)w1, (int)w2, (int)w3});
        }
#pragma unroll
        for (int kt = 0; kt < 4; ++kt) {
            acc0 = __builtin_amdgcn_mfma_f32_32x32x16_bf16(af[kt], bf[kt][0], acc0, 0, 0, 0);
            acc1 = __builtin_amdgcn_mfma_f32_32x32x16_bf16(af[kt], bf[kt][1], acc1, 0, 0, 0);
            accL = __builtin_amdgcn_mfma_f32_32x32x16_bf16(af[kt], onesf,    accL, 0, 0, 0);
        }
    }

    // ---- j-split combine (plain sums) + normalize + store ----
    __shared__ float red[2][64][49];
    if (jp == 1) {
#pragma unroll
        for (int i = 0; i < 16; ++i) {
            red[rw][l][i]      = acc0[i];
            red[rw][l][16 + i] = acc1[i];
            red[rw][l][32 + i] = accL[i];
        }
    }
    __syncthreads();
    if (jp == 0) {
#pragma unroll
        for (int i = 0; i < 16; ++i) {
            acc0[i] += red[rw][l][i];
            acc1[i] += red[rw][l][16 + i];
            accL[i] += red[rw][l][32 + i];
        }
#pragma unroll
        for (int reg = 0; reg < 16; ++reg) {
            int rowc = (reg & 3) + 8 * (reg >> 2) + 4 * kh;
            float linv = 1.0f / accL[reg];
            float* op = out + ((size_t)(bb * Nv + r0 + rowc)) * (NH * FOUT) + hh * FOUT + ch * 64;
            op[lo32]      = acc0[reg] * linv;
            op[32 + lo32] = acc1[reg] * linv;
        }
    }
}

extern "C" void kernel_launch(void* const* d_in, const int* in_sizes, int n_in,
                              void* d_out, int out_size, void* d_ws, size_t ws_size,
                              hipStream_t stream) {
    const float* h   = (const float*)d_in[0];
    const int*   adj = (const int*)d_in[1];
    const float* W   = (const float*)d_in[2];
    const float* a   = (const float*)d_in[3];
    float*       out = (float*)d_out;

    char* ws = (char*)d_ws;
    unsigned short* whf  = (unsigned short*)ws;                  // 8.39 MB
    u64*            adjp = (u64*)(ws + 8388608);                 // 4.19 MB
    float* si = (float*)(ws + 8388608 + 4194304);
    float* sj = si + (size_t)Bv * NH * Nv;
    float* wa = sj + (size_t)Bv * NH * Nv;

    wa_kernel  <<<dim3(2),    dim3(256), 0, stream>>>(W, a, wa);
    prep_kernel<<<dim3(8704), dim3(256), 0, stream>>>(h, W, adj, wa, adjp, whf, si, sj);
    gat_attn_kernel<<<dim3(1024), dim3(256), 0, stream>>>(adjp, whf, si, sj, out);
}